// Round 7
// baseline (115.750 us; speedup 1.0000x reference)
//
#include <hip/hip_runtime.h>
#include <hip/hip_bf16.h>
#include <math.h>

typedef unsigned short u16;
typedef unsigned int   u32;
typedef unsigned char  u8;

#define NB  128
#define NLT 64
#define NLC 400
#define NL  464
#define ND  768
#define NH  3072
#define NEGF (-1e20f)

typedef __attribute__((ext_vector_type(8))) short bf16x8;
typedef __attribute__((ext_vector_type(4))) float f32x4;

__device__ __forceinline__ float b2f(u16 u){ return __uint_as_float(((u32)u)<<16); }
__device__ __forceinline__ u16 f2b(float f){
  u32 x = __float_as_uint(f);
  x += 0x7fffu + ((x>>16)&1u);
  return (u16)(x>>16);
}
template<bool BF> __device__ __forceinline__ float ldf(const void* p, size_t i){
  if constexpr (BF) return b2f(((const u16*)p)[i]);
  else              return ((const float*)p)[i];
}

// ---------------------------------------------------------------- inline ABI detect
__device__ __forceinline__ void detect_inline(const void* tem, const void* tmask,
                                              int* sh2, int& bf, int& m8){
  int tid = threadIdx.x;
  if (tid < 64){
    const u16* p = (const u16*)tem;
    float acc = 0.f;
    for (int i = tid; i < 512; i += 64){
      float v = fabsf(b2f(p[i]));
      acc += fminf(v, 1e10f);               // NaN -> 1e10, inf clamped
    }
    for (int o = 32; o; o >>= 1) acc += __shfl_down(acc, o);
    const u8* mb = (const u8*)tmask;
    int nz = 0;
    for (int i = tid; i < 400; i += 64) if ((i & 3) != 0 && mb[i] != 0) nz = 1;
    unsigned long long anym = __ballot(nz);
    if (tid == 0){ sh2[0] = (acc < 1e4f) ? 1 : 0; sh2[1] = anym ? 1 : 0; }
  }
  __syncthreads();
  bf = sh2[0]; m8 = sh2[1];
}

// ---------------------------------------------------------------- sim part (+ bf16 row copy when f32 input)
template<bool BF>
__device__ void sim_body(const void* tem, const void* ctx, const void* cls,
                         const void* lsp, float* sim, u16* __restrict__ tgtb,
                         int b, int tile,
                         float* clsf, float* red4, float* cnorm)
{
  int tid = threadIdx.x;
  for (int i = tid; i < ND; i += 256) clsf[i] = ldf<BF>(cls, (size_t)b*ND + i);
  __syncthreads();
  float ss = 0.f;
  for (int i = tid; i < ND; i += 256) ss += clsf[i]*clsf[i];
  for (int off = 32; off; off >>= 1) ss += __shfl_down(ss, off);
  if ((tid & 63) == 0) red4[tid >> 6] = ss;
  __syncthreads();
  if (tid == 0) *cnorm = fmaxf(sqrtf(red4[0]+red4[1]+red4[2]+red4[3]), 1e-12f);
  __syncthreads();
  float cn = *cnorm;
  float escale = expf(ldf<BF>(lsp, 0));
  int lane = tid & 63, w = tid >> 6;
  float creg[12];
  #pragma unroll
  for (int j = 0; j < 12; j++) creg[j] = clsf[lane*12 + j];

  for (int rr = 0; rr < 4; rr++){
    int l = tile*16 + w + rr*4;
    float v[12];
    if constexpr (BF){
      const u16* row = (l < NLT) ? ((const u16*)tem + ((size_t)b*NLT + l)*ND)
                                 : ((const u16*)ctx + ((size_t)b*NLC + (l-NLT))*ND);
      const ushort4* rp = (const ushort4*)(row + lane*12);
      #pragma unroll
      for (int q = 0; q < 3; q++){
        ushort4 u = rp[q];
        v[q*4+0]=b2f(u.x); v[q*4+1]=b2f(u.y); v[q*4+2]=b2f(u.z); v[q*4+3]=b2f(u.w);
      }
    } else {
      const float* row = (l < NLT) ? ((const float*)tem + ((size_t)b*NLT + l)*ND)
                                   : ((const float*)ctx + ((size_t)b*NLC + (l-NLT))*ND);
      const float4* rp = (const float4*)(row + lane*12);
      #pragma unroll
      for (int q = 0; q < 3; q++){
        float4 u = rp[q];
        v[q*4+0]=u.x; v[q*4+1]=u.y; v[q*4+2]=u.z; v[q*4+3]=u.w;
      }
      // bf16 side-copy for the second (token) pass: wave writes contiguous row
      u16* orow = tgtb + ((size_t)b*NL + l)*ND + lane*12;
      ushort4 s0 = { f2b(v[0]), f2b(v[1]), f2b(v[2]),  f2b(v[3]) };
      ushort4 s1 = { f2b(v[4]), f2b(v[5]), f2b(v[6]),  f2b(v[7]) };
      ushort4 s2 = { f2b(v[8]), f2b(v[9]), f2b(v[10]), f2b(v[11]) };
      *(ushort4*)(orow + 0) = s0;
      *(ushort4*)(orow + 4) = s1;
      *(ushort4*)(orow + 8) = s2;
    }
    float dot = 0.f, rs = 0.f;
    #pragma unroll
    for (int j = 0; j < 12; j++){ dot += creg[j]*v[j]; rs += v[j]*v[j]; }
    for (int off = 32; off; off >>= 1){
      dot += __shfl_down(dot, off); rs += __shfl_down(rs, off);
    }
    if (lane == 0){
      float rn = fmaxf(sqrtf(rs), 1e-12f);
      sim[(size_t)b*NL + l] = dot / (cn*rn) * escale;
    }
  }
}

// ---------------------------------------------------------------- fused prep(transpose) + sim
// grid 4864 flat: [0,576) w1 transpose tiles, [576,1152) w2, [1152,4864) sim (b*29+tile).
__global__ __launch_bounds__(256) void k_presim(const void* tem, const void* tmask,
    const void* ctx, const void* cls, const void* lsp,
    const void* w1, const void* w2, u16* __restrict__ w1t, u16* __restrict__ w2t,
    float* sim, u16* tgtb, int* flags)
{
  __shared__ int sh2[2];
  __shared__ u16 tile[64][66];
  __shared__ float clsf[ND];
  __shared__ float red4[4];
  __shared__ float cnorm;
  int bf, m8;
  detect_inline(tem, tmask, sh2, bf, m8);
  int bid = blockIdx.x;
  if (bid == 0 && threadIdx.x == 0){ flags[0] = bf; flags[1] = m8; }

  if (bid < 1152){
    int which = (bid >= 576) ? 1 : 0;
    int t = which ? bid - 576 : bid;
    const void* W = which ? w2 : w1;
    u16* Wt = which ? w2t : w1t;
    int K = which ? NH : ND;     // source rows
    int N = which ? ND : NH;     // source cols
    int nt = N >> 6;
    int tk = t / nt, tn = t - tk*nt;
    int k0 = tk*64, n0 = tn*64;
    int r = threadIdx.x >> 6, c = threadIdx.x & 63;
    #pragma unroll
    for (int i = 0; i < 16; i++){
      int row = i*4 + r;
      size_t idx = (size_t)(k0 + row)*N + n0 + c;   // coalesced
      tile[row][c] = bf ? ((const u16*)W)[idx] : f2b(((const float*)W)[idx]);
    }
    __syncthreads();
    #pragma unroll
    for (int i = 0; i < 16; i++){
      int nrow = i*4 + r;
      Wt[(size_t)(n0 + nrow)*K + k0 + c] = tile[c][nrow];  // coalesced
    }
  } else {
    int sid = bid - 1152;
    int b = sid / 29, tl = sid - b*29;
    if (bf) sim_body<true >(tem, ctx, cls, lsp, sim, tgtb, b, tl, clsf, red4, &cnorm);
    else    sim_body<false>(tem, ctx, cls, lsp, sim, tgtb, b, tl, clsf, red4, &cnorm);
  }
}

// ---------------------------------------------------------------- fast 512-thread reductions
__device__ __forceinline__ float bsum512(float v, float* l8, int tid){
  #pragma unroll
  for (int o = 32; o; o >>= 1) v += __shfl_xor(v, o);
  __syncthreads();
  if ((tid & 63) == 0) l8[tid >> 6] = v;
  __syncthreads();
  float s = l8[0];
  #pragma unroll
  for (int i = 1; i < 8; i++) s += l8[i];
  return s;
}
__device__ __forceinline__ float bmax512(float v, float* l8, int tid){
  #pragma unroll
  for (int o = 32; o; o >>= 1) v = fmaxf(v, __shfl_xor(v, o));
  __syncthreads();
  if ((tid & 63) == 0) l8[tid >> 6] = v;
  __syncthreads();
  float s = l8[0];
  #pragma unroll
  for (int i = 1; i < 8; i++) s = fmaxf(s, l8[i]);
  return s;
}
__device__ __forceinline__ float bmin512(float v, float* l8, int tid){
  #pragma unroll
  for (int o = 32; o; o >>= 1) v = fminf(v, __shfl_xor(v, o));
  __syncthreads();
  if ((tid & 63) == 0) l8[tid >> 6] = v;
  __syncthreads();
  float s = l8[0];
  #pragma unroll
  for (int i = 1; i < 8; i++) s = fminf(s, l8[i]);
  return s;
}

// ---------------------------------------------------------------- scores
template<bool M8>
__device__ void scores_body(const float* sim, const void* tmask, const void* cmask,
                            float* tgts, float* diss, float* bgds,
                            float* srt, float* wsum, float* l8)
{
  int b = blockIdx.x, tid = threadIdx.x;
  int lane = tid & 63, wid = tid >> 6;
  bool valid = tid < NL;
  float sv = valid ? sim[(size_t)b*NL + tid] : 0.f;
  bool mk = false;
  if (valid){
    if constexpr (M8)
      mk = (tid < NLT) ? (((const u8*)tmask)[b*NLT + tid] != 0)
                       : (((const u8*)cmask)[b*NLC + tid - NLT] != 0);
    else
      mk = (tid < NLT) ? (((const int*)tmask)[b*NLT + tid] != 0)
                       : (((const int*)cmask)[b*NLC + tid - NLT] != 0);
  }
  float lt = (valid && mk) ? sv : NEGF;
  float m1 = bmax512(lt, l8, tid);
  float e1 = valid ? expf(lt - m1) : 0.f;
  float s1 = bsum512(e1, l8, tid);
  if (valid) tgts[(size_t)b*NL + tid] = e1/s1;

  float bl = (valid && !mk) ? sv : NEGF;
  float m2 = bmax512(bl, l8, tid);
  float e2 = valid ? expf(bl - m2) : 0.f;
  float s2 = bsum512(e2, l8, tid);
  float bg0 = e2/s2;

  // bitonic sort ascending; pads carry +inf
  float v = valid ? bg0 : INFINITY;
  for (int k = 2; k <= 512; k <<= 1){
    for (int j = k >> 1; j >= 64; j >>= 1){
      __syncthreads();
      srt[tid] = v;
      __syncthreads();
      float p = srt[tid ^ j];
      bool up = ((tid & k) == 0), lower = ((tid & j) == 0);
      v = (up == lower) ? fminf(v, p) : fmaxf(v, p);
    }
    int j0 = (k >> 1) < 32 ? (k >> 1) : 32;
    for (int j = j0; j >= 1; j >>= 1){
      float p = __shfl_xor(v, j);
      bool up = ((tid & k) == 0), lower = ((tid & j) == 0);
      v = (up == lower) ? fminf(v, p) : fmaxf(v, p);
    }
  }
  // inclusive scan
  float c = v;
  #pragma unroll
  for (int o = 1; o < 64; o <<= 1){
    float t = __shfl_up(c, o);
    if (lane >= o) c += t;
  }
  __syncthreads();
  if (lane == 63) wsum[wid] = c;
  __syncthreads();
  float off = 0.f;
  for (int i = 0; i < wid; i++) off += wsum[i];
  c += off;
  float cand = (c < 0.25f) ? 1.0f : v;
  float thr = bmin512(cand, l8, tid);

  bool dm = valid && (bg0 >= thr);
  float dl = dm ? bl : NEGF;
  float l2 = dm ? NEGF : bl;
  float m3 = bmax512(dl, l8, tid);
  float e3 = valid ? expf(dl - m3) : 0.f;
  float s3 = bsum512(e3, l8, tid);
  if (valid) diss[(size_t)b*NL + tid] = e3/s3;
  float m4 = bmax512(l2, l8, tid);
  float e4 = valid ? expf(l2 - m4) : 0.f;
  float s4 = bsum512(e4, l8, tid);
  if (valid) bgds[(size_t)b*NL + tid] = e4/s4;
}
__global__ __launch_bounds__(512) void k_scores(const int* flags, const float* sim,
    const void* tmask, const void* cmask, float* tgts, float* diss, float* bgds){
  __shared__ float srt[512];
  __shared__ float wsum[8];
  __shared__ float l8[8];
  if (flags[1]) scores_body<true >(sim, tmask, cmask, tgts, diss, bgds, srt, wsum, l8);
  else          scores_body<false>(sim, tmask, cmask, tgts, diss, bgds, srt, wsum, l8);
}

// ---------------------------------------------------------------- tokens + src0 (fused)
// Reads bf16 rows: originals when input is bf16, else the sim-pass side-copy.
template<bool BF>
__device__ void tok_body(const void* tem, const void* ctx, const u16* __restrict__ tgtb,
                         const void* cls, const void* qe,
                         const float* __restrict__ tgts, const float* __restrict__ diss,
                         const float* __restrict__ bgds,
                         float* __restrict__ src0f, u16* __restrict__ src0b,
                         float (*ws)[NL], float (*red)[3][264])
{
  int b = blockIdx.x, dc = blockIdx.y, tid = threadIdx.x;
  int g = tid >> 5, l32 = tid & 31;
  int c0 = dc*256 + l32*8;
  for (int i = tid; i < NL; i += 256){
    ws[0][i] = tgts[(size_t)b*NL + i];
    ws[1][i] = diss[(size_t)b*NL + i];
    ws[2][i] = bgds[(size_t)b*NL + i];
  }
  __syncthreads();
  float acc[3][8];
  #pragma unroll
  for (int j = 0; j < 3; j++)
    #pragma unroll
    for (int q = 0; q < 8; q++) acc[j][q] = 0.f;

  for (int it = 0; it < 58; it++){
    int l = it*8 + g;
    const u16* row;
    if constexpr (BF){
      row = (l < NLT) ? ((const u16*)tem + ((size_t)b*NLT + l)*ND)
                      : ((const u16*)ctx + ((size_t)b*NLC + (l-NLT))*ND);
    } else {
      row = tgtb + ((size_t)b*NL + l)*ND;
    }
    uint4 v = *(const uint4*)(row + c0);
    float f[8];
    f[0]=b2f((u16)(v.x&0xffff)); f[1]=b2f((u16)(v.x>>16));
    f[2]=b2f((u16)(v.y&0xffff)); f[3]=b2f((u16)(v.y>>16));
    f[4]=b2f((u16)(v.z&0xffff)); f[5]=b2f((u16)(v.z>>16));
    f[6]=b2f((u16)(v.w&0xffff)); f[7]=b2f((u16)(v.w>>16));
    float w0 = ws[0][l], w1 = ws[1][l], w2 = ws[2][l];
    #pragma unroll
    for (int q = 0; q < 8; q++){
      acc[0][q] = fmaf(w0, f[q], acc[0][q]);
      acc[1][q] = fmaf(w1, f[q], acc[1][q]);
      acc[2][q] = fmaf(w2, f[q], acc[2][q]);
    }
  }
  #pragma unroll
  for (int j = 0; j < 3; j++)
    #pragma unroll
    for (int q = 0; q < 8; q++) red[g][j][l32*8 + q] = acc[j][q];
  __syncthreads();
  int col = dc*256 + tid;
  #pragma unroll
  for (int j = 0; j < 3; j++){
    float s = 0.f;
    #pragma unroll
    for (int g2 = 0; g2 < 8; g2++) s += red[g2][j][tid];
    s += ldf<BF>(qe, (size_t)j*ND + col);
    if (j == 0) s += ldf<BF>(cls, (size_t)b*ND + col);
    size_t oi = ((size_t)b*3 + j)*ND + col;
    src0f[oi] = s;
    src0b[oi] = f2b(s);
  }
}
__global__ __launch_bounds__(256) void k_tok(const int* flags, const void* tem,
    const void* ctx, const u16* tgtb, const void* cls, const void* qe,
    const float* tgts, const float* diss, const float* bgds,
    float* src0f, u16* src0b){
  __shared__ float ws[3][NL];
  __shared__ float red[8][3][264];
  if (flags[0]) tok_body<true >(tem, ctx, tgtb, cls, qe, tgts, diss, bgds, src0f, src0b, ws, red);
  else          tok_body<false>(tem, ctx, tgtb, cls, qe, tgts, diss, bgds, src0f, src0b, ws, red);
}

// ---------------------------------------------------------------- MFMA GEMM core
// Both operands bf16 with [row][K] layout (B pre-transposed). 2-phase dbuf.
__device__ __forceinline__ void mfma_loop2(const u16* __restrict__ A, int lda,
                                           const u16* __restrict__ B, int ldb,
                                           int m0, int n0, int kb_, int ke_,
                                           u16* lds, f32x4 (&acc)[2][2])
{
  int tid = threadIdx.x, lane = tid & 63;
  int w = tid >> 6, wr = w >> 1, wc = w & 1;
  #pragma unroll
  for (int i = 0; i < 2; i++)
    #pragma unroll
    for (int j = 0; j < 2; j++) acc[i][j] = (f32x4){0.f,0.f,0.f,0.f};

  int rS = tid >> 2, kcS = (tid & 3) * 16;
  uint4 a0, a1, b0, b1;
  auto LOAD = [&](int k0){
    const uint4* pa = (const uint4*)(A + (size_t)(m0 + rS)*lda + k0 + kcS);
    a0 = pa[0]; a1 = pa[1];
    const uint4* pb = (const uint4*)(B + (size_t)(n0 + rS)*ldb + k0 + kcS);
    b0 = pb[0]; b1 = pb[1];
  };
  auto WRITE = [&](u16* L){
    u32 sw = (u32)((rS & 7) << 4);
    u32 ba = (u32)(rS*128 + kcS*2);
    *(uint4*)((char*)L + (ba ^ sw)) = a0;
    *(uint4*)((char*)L + ((ba + 16) ^ sw)) = a1;
    *(uint4*)((char*)L + 8192 + (ba ^ sw)) = b0;
    *(uint4*)((char*)L + 8192 + ((ba + 16) ^ sw)) = b1;
  };

  int nt = (ke_ - kb_) >> 6;
  LOAD(kb_);
  WRITE(lds);
  __syncthreads();
  int cur = 0;
  for (int t = 0; t < nt; t++){
    if (t + 1 < nt) LOAD(kb_ + (t+1)*64);
    u16* L = lds + (size_t)cur*8192;
    #pragma unroll
    for (int kb = 0; kb < 2; kb++){
      bf16x8 af[2], bfr[2];
      #pragma unroll
      for (int i = 0; i < 2; i++){
        int ml = wr*32 + i*16 + (lane & 15);
        u32 ab = (u32)(ml*128 + kb*64 + (lane >> 4)*16) ^ (u32)((ml & 7) << 4);
        af[i] = *(const bf16x8*)((char*)L + ab);
        int cl = wc*32 + i*16 + (lane & 15);
        u32 bb = (u32)(cl*128 + kb*64 + (lane >> 4)*16) ^ (u32)((cl & 7) << 4);
        bfr[i] = *(const bf16x8*)((char*)L + 8192 + bb);
      }
      #pragma unroll
      for (int i = 0; i < 2; i++)
        #pragma unroll
        for (int j = 0; j < 2; j++)
          acc[i][j] = __builtin_amdgcn_mfma_f32_16x16x32_bf16(af[i], bfr[j], acc[i][j], 0, 0, 0);
    }
    if (t + 1 < nt) WRITE(lds + (size_t)(cur^1)*8192);
    __syncthreads();
    cur ^= 1;
  }
}

// fc1: h = gelu(src0b @ w1 + b1), bf16 out. grid (NH/64, 384/64)
template<bool BF>
__device__ void fc1_body(const u16* src0b, const u16* w1t, const void* b1, u16* hbf, u16* lds){
  int n0 = blockIdx.x*64, m0 = blockIdx.y*64;
  f32x4 acc[2][2];
  mfma_loop2(src0b, ND, w1t, ND, m0, n0, 0, ND, lds, acc);
  int lane = threadIdx.x & 63, w = threadIdx.x >> 6, wr = w >> 1, wc = w & 1;
  #pragma unroll
  for (int j = 0; j < 2; j++){
    int n = n0 + wc*32 + j*16 + (lane & 15);
    float bb = ldf<BF>(b1, n);
    #pragma unroll
    for (int i = 0; i < 2; i++){
      int mb = m0 + wr*32 + i*16 + (lane >> 4)*4;
      #pragma unroll
      for (int r = 0; r < 4; r++){
        float x = acc[i][j][r] + bb;
        float g = 0.5f*x*(1.0f + erff(x*0.70710678118654752f));
        hbf[(size_t)(mb + r)*NH + n] = f2b(g);
      }
    }
  }
}
__global__ __launch_bounds__(256) void k_fc1(const int* flags, const u16* src0b,
    const u16* w1t, const void* b1, u16* hbf){
  __shared__ u16 lds[16384];
  if (flags[0]) fc1_body<true >(src0b, w1t, b1, hbf, lds);
  else          fc1_body<false>(src0b, w1t, b1, hbf, lds);
}

// fc2 partials: grid (ND/64, 384/64, 4)
__global__ __launch_bounds__(256) void k_fc2(const int* flags, const u16* hbf,
    const u16* w2t, float* fc2p){
  __shared__ u16 lds[16384];
  int n0 = blockIdx.x*64, m0 = blockIdx.y*64, z = blockIdx.z;
  f32x4 acc[2][2];
  mfma_loop2(hbf, NH, w2t, NH, m0, n0, z*768, (z+1)*768, lds, acc);
  int lane = threadIdx.x & 63, w = threadIdx.x >> 6, wr = w >> 1, wc = w & 1;
  float* po = fc2p + (size_t)z*(384*ND);
  #pragma unroll
  for (int j = 0; j < 2; j++){
    int n = n0 + wc*32 + j*16 + (lane & 15);
    #pragma unroll
    for (int i = 0; i < 2; i++){
      int mb = m0 + wr*32 + i*16 + (lane >> 4)*4;
      #pragma unroll
      for (int r = 0; r < 4; r++)
        po[(size_t)(mb + r)*ND + n] = acc[i][j][r];
    }
  }
}

// ---------------------------------------------------------------- fc2 epilogue
template<bool BF>
__device__ void fin_body(const float* __restrict__ p, const void* b2,
                         const float* __restrict__ src0f, const void* cls,
                         const void* qe, const int* flag, void* out){
  int idx = (blockIdx.x*256 + threadIdx.x)*4;
  int r = idx / ND;
  int n = idx % ND;
  float s[4] = {0,0,0,0};
  #pragma unroll
  for (int ksp = 0; ksp < 4; ksp++){
    float4 v = *(const float4*)(p + (size_t)ksp*(384*ND) + idx);
    s[0]+=v.x; s[1]+=v.y; s[2]+=v.z; s[3]+=v.w;
  }
  float4 res = *(const float4*)(src0f + idx);
  const float* rp = &res.x;
  int bi = r/3, j = r - bi*3;
  bool take_src_ = (flag[bi] == 1);
  #pragma unroll
  for (int jj = 0; jj < 4; jj++){
    float val = s[jj] + ldf<BF>(b2, n + jj) + rp[jj];
    if (take_src_){
      val = ldf<BF>(qe, (size_t)j*ND + n + jj)
          + ((j == 0) ? ldf<BF>(cls, (size_t)bi*ND + n + jj) : 0.f);
    }
    s[jj] = val;
  }
  if constexpr (BF){
    ushort4 o = { f2b(s[0]), f2b(s[1]), f2b(s[2]), f2b(s[3]) };
    *(ushort4*)((u16*)out + idx) = o;
  } else {
    float4 o = {s[0], s[1], s[2], s[3]};
    *(float4*)((float*)out + idx) = o;
  }
}
__global__ __launch_bounds__(256) void k_fin(const int* flags, const float* p,
    const void* b2, const float* src0f, const void* cls, const void* qe,
    const int* flag, void* out){
  if (flags[0]) fin_body<true >(p, b2, src0f, cls, qe, flag, out);
  else          fin_body<false>(p, b2, src0f, cls, qe, flag, out);
}

// ---------------------------------------------------------------- launch
extern "C" void kernel_launch(void* const* d_in, const int* in_sizes, int n_in,
                              void* d_out, int out_size, void* d_ws, size_t ws_size,
                              hipStream_t stream)
{
  const void* tem   = d_in[0];
  const void* tmask = d_in[1];
  const void* ctx   = d_in[2];
  const void* cmask = d_in[3];
  const void* cls   = d_in[4];
  const int*  flag  = (const int*)d_in[5];
  const void* qe    = d_in[6];
  const void* ls    = d_in[7];
  const void* w1    = d_in[8];
  const void* b1    = d_in[9];
  const void* w2    = d_in[10];
  const void* b2    = d_in[11];

  int*   flags = (int*)d_ws;
  float* p     = (float*)d_ws + 16;
  float* sim   = p;  p += (size_t)NB*NL;
  float* tgts  = p;  p += (size_t)NB*NL;
  float* diss  = p;  p += (size_t)NB*NL;
  float* bgds  = p;  p += (size_t)NB*NL;
  float* src0f = p;  p += (size_t)384*ND;
  u16*   src0b = (u16*)p; p += (size_t)384*ND/2;
  u16*   hbf   = (u16*)p; p += (size_t)384*NH/2;
  float* fc2p  = p;  p += (size_t)4*384*ND;
  u16*   w1t   = (u16*)p; p += (size_t)ND*NH/2;
  u16*   w2t   = (u16*)p; p += (size_t)ND*NH/2;
  u16*   tgtb  = (u16*)p; p += (size_t)NB*NL*ND/2;   // 91 MB bf16 row copy

  hipLaunchKernelGGL(k_presim, dim3(1152 + NB*29), dim3(256), 0, stream,
                     tem, tmask, ctx, cls, ls, w1, w2, w1t, w2t, sim, tgtb, flags);
  hipLaunchKernelGGL(k_scores, dim3(NB), dim3(512), 0, stream, flags, sim, tmask, cmask, tgts, diss, bgds);
  hipLaunchKernelGGL(k_tok,    dim3(NB, 3), dim3(256), 0, stream,
                     flags, tem, ctx, tgtb, cls, qe, tgts, diss, bgds, src0f, src0b);
  hipLaunchKernelGGL(k_fc1,    dim3(NH/64, 384/64), dim3(256), 0, stream, flags, src0b, w1t, b1, hbf);
  hipLaunchKernelGGL(k_fc2,    dim3(ND/64, 384/64, 4), dim3(256), 0, stream, flags, hbf, w2t, fc2p);
  hipLaunchKernelGGL(k_fin,    dim3(384*ND/1024), dim3(256), 0, stream,
                     flags, fc2p, b2, src0f, cls, qe, flag, d_out);
}

// Round 8
// 104.120 us; speedup vs baseline: 1.1117x; 1.1117x over previous
//
#include <hip/hip_runtime.h>
#include <hip/hip_bf16.h>
#include <math.h>

typedef unsigned short u16;
typedef unsigned int   u32;
typedef unsigned char  u8;

#define NB  128
#define NLT 64
#define NLC 400
#define NL  464
#define ND  768
#define NH  3072
#define NEGF (-1e20f)

typedef __attribute__((ext_vector_type(8))) short bf16x8;
typedef __attribute__((ext_vector_type(4))) float f32x4;

__device__ __forceinline__ float b2f(u16 u){ return __uint_as_float(((u32)u)<<16); }
__device__ __forceinline__ u16 f2b(float f){
  u32 x = __float_as_uint(f);
  x += 0x7fffu + ((x>>16)&1u);
  return (u16)(x>>16);
}
template<bool BF> __device__ __forceinline__ float ldf(const void* p, size_t i){
  if constexpr (BF) return b2f(((const u16*)p)[i]);
  else              return ((const float*)p)[i];
}

// ---------------------------------------------------------------- inline ABI detect
__device__ __forceinline__ void detect_inline(const void* tem, const void* tmask,
                                              int* sh2, int& bf, int& m8){
  int tid = threadIdx.x;
  if (tid < 64){
    const u16* p = (const u16*)tem;
    float acc = 0.f;
    for (int i = tid; i < 512; i += 64){
      float v = fabsf(b2f(p[i]));
      acc += fminf(v, 1e10f);               // NaN -> 1e10, inf clamped
    }
    for (int o = 32; o; o >>= 1) acc += __shfl_down(acc, o);
    const u8* mb = (const u8*)tmask;
    int nz = 0;
    for (int i = tid; i < 400; i += 64) if ((i & 3) != 0 && mb[i] != 0) nz = 1;
    unsigned long long anym = __ballot(nz);
    if (tid == 0){ sh2[0] = (acc < 1e4f) ? 1 : 0; sh2[1] = anym ? 1 : 0; }
  }
  __syncthreads();
  bf = sh2[0]; m8 = sh2[1];
}

// ---------------------------------------------------------------- sim: lane owns a row (no cross-lane reduce)
// block = 256 thr, handles 232 rows of batch b (half h). Lane streams its row,
// cls from LDS (uniform index -> broadcast), dot/rs in registers.
template<bool BF>
__device__ void sim_body(const void* tem, const void* ctx, const void* cls,
                         const void* lsp, float* sim, int b, int h,
                         float* clsf, float* l4)
{
  int tid = threadIdx.x;
  for (int i = tid; i < ND; i += 256) clsf[i] = ldf<BF>(cls, (size_t)b*ND + i);
  __syncthreads();
  float ss = 0.f;
  for (int i = tid; i < ND; i += 256) ss += clsf[i]*clsf[i];
  #pragma unroll
  for (int o = 32; o; o >>= 1) ss += __shfl_xor(ss, o);
  if ((tid & 63) == 0) l4[tid >> 6] = ss;
  __syncthreads();
  float cn = fmaxf(sqrtf(l4[0]+l4[1]+l4[2]+l4[3]), 1e-12f);
  float escale = expf(ldf<BF>(lsp, 0));

  if (tid >= 232) return;
  int l = h*232 + tid;
  float d0=0,d1=0,d2=0,d3=0, s0=0,s1=0,s2=0,s3=0;
  const float4* c4 = (const float4*)clsf;

  if constexpr (BF){
    const u16* row = (l < NLT) ? ((const u16*)tem + ((size_t)b*NLT + l)*ND)
                               : ((const u16*)ctx + ((size_t)b*NLC + (l-NLT))*ND);
    const uint4* r8 = (const uint4*)row;               // 8 bf16 per uint4
    for (int k = 0; k < 96; k += 16){
      #pragma unroll
      for (int q = 0; q < 16; q++){
        uint4 rv = r8[k+q];
        float4 ca = c4[(k+q)*2], cb = c4[(k+q)*2+1];   // uniform -> LDS broadcast
        float f0=b2f((u16)(rv.x&0xffff)), f1=b2f((u16)(rv.x>>16));
        float f2=b2f((u16)(rv.y&0xffff)), f3=b2f((u16)(rv.y>>16));
        float f4=b2f((u16)(rv.z&0xffff)), f5=b2f((u16)(rv.z>>16));
        float f6=b2f((u16)(rv.w&0xffff)), f7=b2f((u16)(rv.w>>16));
        d0=fmaf(f0,ca.x,d0); s0=fmaf(f0,f0,s0);
        d1=fmaf(f1,ca.y,d1); s1=fmaf(f1,f1,s1);
        d2=fmaf(f2,ca.z,d2); s2=fmaf(f2,f2,s2);
        d3=fmaf(f3,ca.w,d3); s3=fmaf(f3,f3,s3);
        d0=fmaf(f4,cb.x,d0); s0=fmaf(f4,f4,s0);
        d1=fmaf(f5,cb.y,d1); s1=fmaf(f5,f5,s1);
        d2=fmaf(f6,cb.z,d2); s2=fmaf(f6,f6,s2);
        d3=fmaf(f7,cb.w,d3); s3=fmaf(f7,f7,s3);
      }
    }
  } else {
    const float* row = (l < NLT) ? ((const float*)tem + ((size_t)b*NLT + l)*ND)
                                 : ((const float*)ctx + ((size_t)b*NLC + (l-NLT))*ND);
    const float4* r4 = (const float4*)row;
    for (int k = 0; k < 192; k += 16){
      #pragma unroll
      for (int q = 0; q < 16; q++){
        float4 rv = r4[k+q];
        float4 cv = c4[k+q];                           // uniform -> LDS broadcast
        d0=fmaf(rv.x,cv.x,d0); s0=fmaf(rv.x,rv.x,s0);
        d1=fmaf(rv.y,cv.y,d1); s1=fmaf(rv.y,rv.y,s1);
        d2=fmaf(rv.z,cv.z,d2); s2=fmaf(rv.z,rv.z,s2);
        d3=fmaf(rv.w,cv.w,d3); s3=fmaf(rv.w,rv.w,s3);
      }
    }
  }
  float dot = (d0+d1)+(d2+d3);
  float rs  = (s0+s1)+(s2+s3);
  float rn = fmaxf(sqrtf(rs), 1e-12f);
  sim[(size_t)b*NL + l] = dot/(cn*rn)*escale;
}

// ---------------------------------------------------------------- fused sim + weight transpose
// grid 1408 flat: [0,256) sim (b = bid>>1, h = bid&1); [256,1408) transpose tiles.
__global__ __launch_bounds__(256) void k_presim(const void* tem, const void* tmask,
    const void* ctx, const void* cls, const void* lsp,
    const void* w1, const void* w2, u16* __restrict__ w1t, u16* __restrict__ w2t,
    float* sim, int* flags)
{
  __shared__ int sh2[2];
  __shared__ u16 tile[64][66];
  __shared__ float clsf[ND];
  __shared__ float l4[4];
  int bf, m8;
  detect_inline(tem, tmask, sh2, bf, m8);
  int bid = blockIdx.x;
  if (bid == 0 && threadIdx.x == 0){ flags[0] = bf; flags[1] = m8; }

  if (bid < 256){
    int b = bid >> 1, h = bid & 1;
    if (bf) sim_body<true >(tem, ctx, cls, lsp, sim, b, h, clsf, l4);
    else    sim_body<false>(tem, ctx, cls, lsp, sim, b, h, clsf, l4);
  } else {
    int t = bid - 256;
    int which = (t >= 576) ? 1 : 0;
    if (which) t -= 576;
    const void* W = which ? w2 : w1;
    u16* Wt = which ? w2t : w1t;
    int K = which ? NH : ND;     // source rows
    int N = which ? ND : NH;     // source cols
    int nt = N >> 6;
    int tk = t / nt, tn = t - tk*nt;
    int k0 = tk*64, n0 = tn*64;
    int r = threadIdx.x >> 6, c = threadIdx.x & 63;
    #pragma unroll
    for (int i = 0; i < 16; i++){
      int row = i*4 + r;
      size_t idx = (size_t)(k0 + row)*N + n0 + c;   // coalesced
      tile[row][c] = bf ? ((const u16*)W)[idx] : f2b(((const float*)W)[idx]);
    }
    __syncthreads();
    #pragma unroll
    for (int i = 0; i < 16; i++){
      int nrow = i*4 + r;
      Wt[(size_t)(n0 + nrow)*K + k0 + c] = tile[c][nrow];  // coalesced
    }
  }
}

// ---------------------------------------------------------------- fast 512-thread reductions
__device__ __forceinline__ float bsum512(float v, float* l8, int tid){
  #pragma unroll
  for (int o = 32; o; o >>= 1) v += __shfl_xor(v, o);
  __syncthreads();
  if ((tid & 63) == 0) l8[tid >> 6] = v;
  __syncthreads();
  float s = l8[0];
  #pragma unroll
  for (int i = 1; i < 8; i++) s += l8[i];
  return s;
}
__device__ __forceinline__ float bmax512(float v, float* l8, int tid){
  #pragma unroll
  for (int o = 32; o; o >>= 1) v = fmaxf(v, __shfl_xor(v, o));
  __syncthreads();
  if ((tid & 63) == 0) l8[tid >> 6] = v;
  __syncthreads();
  float s = l8[0];
  #pragma unroll
  for (int i = 1; i < 8; i++) s = fmaxf(s, l8[i]);
  return s;
}
__device__ __forceinline__ float bmin512(float v, float* l8, int tid){
  #pragma unroll
  for (int o = 32; o; o >>= 1) v = fminf(v, __shfl_xor(v, o));
  __syncthreads();
  if ((tid & 63) == 0) l8[tid >> 6] = v;
  __syncthreads();
  float s = l8[0];
  #pragma unroll
  for (int i = 1; i < 8; i++) s = fminf(s, l8[i]);
  return s;
}

// ---------------------------------------------------------------- scores
template<bool M8>
__device__ void scores_body(const float* sim, const void* tmask, const void* cmask,
                            float* tgts, float* diss, float* bgds,
                            float* srt, float* wsum, float* l8)
{
  int b = blockIdx.x, tid = threadIdx.x;
  int lane = tid & 63, wid = tid >> 6;
  bool valid = tid < NL;
  float sv = valid ? sim[(size_t)b*NL + tid] : 0.f;
  bool mk = false;
  if (valid){
    if constexpr (M8)
      mk = (tid < NLT) ? (((const u8*)tmask)[b*NLT + tid] != 0)
                       : (((const u8*)cmask)[b*NLC + tid - NLT] != 0);
    else
      mk = (tid < NLT) ? (((const int*)tmask)[b*NLT + tid] != 0)
                       : (((const int*)cmask)[b*NLC + tid - NLT] != 0);
  }
  float lt = (valid && mk) ? sv : NEGF;
  float m1 = bmax512(lt, l8, tid);
  float e1 = valid ? expf(lt - m1) : 0.f;
  float s1 = bsum512(e1, l8, tid);
  if (valid) tgts[(size_t)b*NL + tid] = e1/s1;

  float bl = (valid && !mk) ? sv : NEGF;
  float m2 = bmax512(bl, l8, tid);
  float e2 = valid ? expf(bl - m2) : 0.f;
  float s2 = bsum512(e2, l8, tid);
  float bg0 = e2/s2;

  // bitonic sort ascending; pads carry +inf
  float v = valid ? bg0 : INFINITY;
  for (int k = 2; k <= 512; k <<= 1){
    for (int j = k >> 1; j >= 64; j >>= 1){
      __syncthreads();
      srt[tid] = v;
      __syncthreads();
      float p = srt[tid ^ j];
      bool up = ((tid & k) == 0), lower = ((tid & j) == 0);
      v = (up == lower) ? fminf(v, p) : fmaxf(v, p);
    }
    int j0 = (k >> 1) < 32 ? (k >> 1) : 32;
    for (int j = j0; j >= 1; j >>= 1){
      float p = __shfl_xor(v, j);
      bool up = ((tid & k) == 0), lower = ((tid & j) == 0);
      v = (up == lower) ? fminf(v, p) : fmaxf(v, p);
    }
  }
  // inclusive scan
  float c = v;
  #pragma unroll
  for (int o = 1; o < 64; o <<= 1){
    float t = __shfl_up(c, o);
    if (lane >= o) c += t;
  }
  __syncthreads();
  if (lane == 63) wsum[wid] = c;
  __syncthreads();
  float off = 0.f;
  for (int i = 0; i < wid; i++) off += wsum[i];
  c += off;
  float cand = (c < 0.25f) ? 1.0f : v;
  float thr = bmin512(cand, l8, tid);

  bool dm = valid && (bg0 >= thr);
  float dl = dm ? bl : NEGF;
  float l2 = dm ? NEGF : bl;
  float m3 = bmax512(dl, l8, tid);
  float e3 = valid ? expf(dl - m3) : 0.f;
  float s3 = bsum512(e3, l8, tid);
  if (valid) diss[(size_t)b*NL + tid] = e3/s3;
  float m4 = bmax512(l2, l8, tid);
  float e4 = valid ? expf(l2 - m4) : 0.f;
  float s4 = bsum512(e4, l8, tid);
  if (valid) bgds[(size_t)b*NL + tid] = e4/s4;
}
__global__ __launch_bounds__(512) void k_scores(const int* flags, const float* sim,
    const void* tmask, const void* cmask, float* tgts, float* diss, float* bgds){
  __shared__ float srt[512];
  __shared__ float wsum[8];
  __shared__ float l8[8];
  if (flags[1]) scores_body<true >(sim, tmask, cmask, tgts, diss, bgds, srt, wsum, l8);
  else          scores_body<false>(sim, tmask, cmask, tgts, diss, bgds, srt, wsum, l8);
}

// ---------------------------------------------------------------- tokens + src0 (fused)
template<bool BF>
__device__ void tok_body(const void* tem, const void* ctx, const void* cls, const void* qe,
                         const float* __restrict__ tgts, const float* __restrict__ diss,
                         const float* __restrict__ bgds,
                         float* __restrict__ src0f, u16* __restrict__ src0b,
                         float (*ws)[NL], float (*red)[3][264])
{
  int b = blockIdx.x, dc = blockIdx.y, tid = threadIdx.x;
  int g = tid >> 5, l32 = tid & 31;
  int c0 = dc*256 + l32*8;
  for (int i = tid; i < NL; i += 256){
    ws[0][i] = tgts[(size_t)b*NL + i];
    ws[1][i] = diss[(size_t)b*NL + i];
    ws[2][i] = bgds[(size_t)b*NL + i];
  }
  __syncthreads();
  float acc[3][8];
  #pragma unroll
  for (int j = 0; j < 3; j++)
    #pragma unroll
    for (int q = 0; q < 8; q++) acc[j][q] = 0.f;

  for (int it = 0; it < 58; it++){
    int l = it*8 + g;
    float f[8];
    if constexpr (BF){
      const u16* row = (l < NLT) ? ((const u16*)tem + ((size_t)b*NLT + l)*ND)
                                 : ((const u16*)ctx + ((size_t)b*NLC + (l-NLT))*ND);
      uint4 v = *(const uint4*)(row + c0);
      f[0]=b2f((u16)(v.x&0xffff)); f[1]=b2f((u16)(v.x>>16));
      f[2]=b2f((u16)(v.y&0xffff)); f[3]=b2f((u16)(v.y>>16));
      f[4]=b2f((u16)(v.z&0xffff)); f[5]=b2f((u16)(v.z>>16));
      f[6]=b2f((u16)(v.w&0xffff)); f[7]=b2f((u16)(v.w>>16));
    } else {
      const float* row = (l < NLT) ? ((const float*)tem + ((size_t)b*NLT + l)*ND)
                                   : ((const float*)ctx + ((size_t)b*NLC + (l-NLT))*ND);
      float4 v0 = *(const float4*)(row + c0);
      float4 v1 = *(const float4*)(row + c0 + 4);
      f[0]=v0.x; f[1]=v0.y; f[2]=v0.z; f[3]=v0.w;
      f[4]=v1.x; f[5]=v1.y; f[6]=v1.z; f[7]=v1.w;
    }
    float w0 = ws[0][l], w1 = ws[1][l], w2 = ws[2][l];
    #pragma unroll
    for (int q = 0; q < 8; q++){
      acc[0][q] = fmaf(w0, f[q], acc[0][q]);
      acc[1][q] = fmaf(w1, f[q], acc[1][q]);
      acc[2][q] = fmaf(w2, f[q], acc[2][q]);
    }
  }
  #pragma unroll
  for (int j = 0; j < 3; j++)
    #pragma unroll
    for (int q = 0; q < 8; q++) red[g][j][l32*8 + q] = acc[j][q];
  __syncthreads();
  int col = dc*256 + tid;
  #pragma unroll
  for (int j = 0; j < 3; j++){
    float s = 0.f;
    #pragma unroll
    for (int g2 = 0; g2 < 8; g2++) s += red[g2][j][tid];
    s += ldf<BF>(qe, (size_t)j*ND + col);
    if (j == 0) s += ldf<BF>(cls, (size_t)b*ND + col);
    size_t oi = ((size_t)b*3 + j)*ND + col;
    src0f[oi] = s;
    src0b[oi] = f2b(s);
  }
}
__global__ __launch_bounds__(256) void k_tok(const int* flags, const void* tem,
    const void* ctx, const void* cls, const void* qe,
    const float* tgts, const float* diss, const float* bgds,
    float* src0f, u16* src0b){
  __shared__ float ws[3][NL];
  __shared__ float red[8][3][264];
  if (flags[0]) tok_body<true >(tem, ctx, cls, qe, tgts, diss, bgds, src0f, src0b, ws, red);
  else          tok_body<false>(tem, ctx, cls, qe, tgts, diss, bgds, src0f, src0b, ws, red);
}

// ---------------------------------------------------------------- MFMA GEMM core
// Both operands bf16 with [row][K] layout (B pre-transposed). 2-phase dbuf.
__device__ __forceinline__ void mfma_loop2(const u16* __restrict__ A, int lda,
                                           const u16* __restrict__ B, int ldb,
                                           int m0, int n0, int kb_, int ke_,
                                           u16* lds, f32x4 (&acc)[2][2])
{
  int tid = threadIdx.x, lane = tid & 63;
  int w = tid >> 6, wr = w >> 1, wc = w & 1;
  #pragma unroll
  for (int i = 0; i < 2; i++)
    #pragma unroll
    for (int j = 0; j < 2; j++) acc[i][j] = (f32x4){0.f,0.f,0.f,0.f};

  int rS = tid >> 2, kcS = (tid & 3) * 16;
  uint4 a0, a1, b0, b1;
  auto LOAD = [&](int k0){
    const uint4* pa = (const uint4*)(A + (size_t)(m0 + rS)*lda + k0 + kcS);
    a0 = pa[0]; a1 = pa[1];
    const uint4* pb = (const uint4*)(B + (size_t)(n0 + rS)*ldb + k0 + kcS);
    b0 = pb[0]; b1 = pb[1];
  };
  auto WRITE = [&](u16* L){
    u32 sw = (u32)((rS & 7) << 4);
    u32 ba = (u32)(rS*128 + kcS*2);
    *(uint4*)((char*)L + (ba ^ sw)) = a0;
    *(uint4*)((char*)L + ((ba + 16) ^ sw)) = a1;
    *(uint4*)((char*)L + 8192 + (ba ^ sw)) = b0;
    *(uint4*)((char*)L + 8192 + ((ba + 16) ^ sw)) = b1;
  };

  int nt = (ke_ - kb_) >> 6;
  LOAD(kb_);
  WRITE(lds);
  __syncthreads();
  int cur = 0;
  for (int t = 0; t < nt; t++){
    if (t + 1 < nt) LOAD(kb_ + (t+1)*64);
    u16* L = lds + (size_t)cur*8192;
    #pragma unroll
    for (int kb = 0; kb < 2; kb++){
      bf16x8 af[2], bfr[2];
      #pragma unroll
      for (int i = 0; i < 2; i++){
        int ml = wr*32 + i*16 + (lane & 15);
        u32 ab = (u32)(ml*128 + kb*64 + (lane >> 4)*16) ^ (u32)((ml & 7) << 4);
        af[i] = *(const bf16x8*)((char*)L + ab);
        int cl = wc*32 + i*16 + (lane & 15);
        u32 bb = (u32)(cl*128 + kb*64 + (lane >> 4)*16) ^ (u32)((cl & 7) << 4);
        bfr[i] = *(const bf16x8*)((char*)L + 8192 + bb);
      }
      #pragma unroll
      for (int i = 0; i < 2; i++)
        #pragma unroll
        for (int j = 0; j < 2; j++)
          acc[i][j] = __builtin_amdgcn_mfma_f32_16x16x32_bf16(af[i], bfr[j], acc[i][j], 0, 0, 0);
    }
    if (t + 1 < nt) WRITE(lds + (size_t)(cur^1)*8192);
    __syncthreads();
    cur ^= 1;
  }
}

// fc1: h = gelu(src0b @ w1 + b1), bf16 out. grid (NH/64, 384/64)
template<bool BF>
__device__ void fc1_body(const u16* src0b, const u16* w1t, const void* b1, u16* hbf, u16* lds){
  int n0 = blockIdx.x*64, m0 = blockIdx.y*64;
  f32x4 acc[2][2];
  mfma_loop2(src0b, ND, w1t, ND, m0, n0, 0, ND, lds, acc);
  int lane = threadIdx.x & 63, w = threadIdx.x >> 6, wr = w >> 1, wc = w & 1;
  #pragma unroll
  for (int j = 0; j < 2; j++){
    int n = n0 + wc*32 + j*16 + (lane & 15);
    float bb = ldf<BF>(b1, n);
    #pragma unroll
    for (int i = 0; i < 2; i++){
      int mb = m0 + wr*32 + i*16 + (lane >> 4)*4;
      #pragma unroll
      for (int r = 0; r < 4; r++){
        float x = acc[i][j][r] + bb;
        float g = 0.5f*x*(1.0f + erff(x*0.70710678118654752f));
        hbf[(size_t)(mb + r)*NH + n] = f2b(g);
      }
    }
  }
}
__global__ __launch_bounds__(256) void k_fc1(const int* flags, const u16* src0b,
    const u16* w1t, const void* b1, u16* hbf){
  __shared__ u16 lds[16384];
  if (flags[0]) fc1_body<true >(src0b, w1t, b1, hbf, lds);
  else          fc1_body<false>(src0b, w1t, b1, hbf, lds);
}

// fc2 partials: grid (ND/64, 384/64, 4)
__global__ __launch_bounds__(256) void k_fc2(const int* flags, const u16* hbf,
    const u16* w2t, float* fc2p){
  __shared__ u16 lds[16384];
  int n0 = blockIdx.x*64, m0 = blockIdx.y*64, z = blockIdx.z;
  f32x4 acc[2][2];
  mfma_loop2(hbf, NH, w2t, NH, m0, n0, z*768, (z+1)*768, lds, acc);
  int lane = threadIdx.x & 63, w = threadIdx.x >> 6, wr = w >> 1, wc = w & 1;
  float* po = fc2p + (size_t)z*(384*ND);
  #pragma unroll
  for (int j = 0; j < 2; j++){
    int n = n0 + wc*32 + j*16 + (lane & 15);
    #pragma unroll
    for (int i = 0; i < 2; i++){
      int mb = m0 + wr*32 + i*16 + (lane >> 4)*4;
      #pragma unroll
      for (int r = 0; r < 4; r++)
        po[(size_t)(mb + r)*ND + n] = acc[i][j][r];
    }
  }
}

// ---------------------------------------------------------------- fc2 epilogue
template<bool BF>
__device__ void fin_body(const float* __restrict__ p, const void* b2,
                         const float* __restrict__ src0f, const void* cls,
                         const void* qe, const int* flag, void* out){
  int idx = (blockIdx.x*256 + threadIdx.x)*4;
  int r = idx / ND;
  int n = idx % ND;
  float s[4] = {0,0,0,0};
  #pragma unroll
  for (int ksp = 0; ksp < 4; ksp++){
    float4 v = *(const float4*)(p + (size_t)ksp*(384*ND) + idx);
    s[0]+=v.x; s[1]+=v.y; s[2]+=v.z; s[3]+=v.w;
  }
  float4 res = *(const float4*)(src0f + idx);
  const float* rp = &res.x;
  int bi = r/3, j = r - bi*3;
  bool take_src_ = (flag[bi] == 1);
  #pragma unroll
  for (int jj = 0; jj < 4; jj++){
    float val = s[jj] + ldf<BF>(b2, n + jj) + rp[jj];
    if (take_src_){
      val = ldf<BF>(qe, (size_t)j*ND + n + jj)
          + ((j == 0) ? ldf<BF>(cls, (size_t)bi*ND + n + jj) : 0.f);
    }
    s[jj] = val;
  }
  if constexpr (BF){
    ushort4 o = { f2b(s[0]), f2b(s[1]), f2b(s[2]), f2b(s[3]) };
    *(ushort4*)((u16*)out + idx) = o;
  } else {
    float4 o = {s[0], s[1], s[2], s[3]};
    *(float4*)((float*)out + idx) = o;
  }
}
__global__ __launch_bounds__(256) void k_fin(const int* flags, const float* p,
    const void* b2, const float* src0f, const void* cls, const void* qe,
    const int* flag, void* out){
  if (flags[0]) fin_body<true >(p, b2, src0f, cls, qe, flag, out);
  else          fin_body<false>(p, b2, src0f, cls, qe, flag, out);
}

// ---------------------------------------------------------------- launch
extern "C" void kernel_launch(void* const* d_in, const int* in_sizes, int n_in,
                              void* d_out, int out_size, void* d_ws, size_t ws_size,
                              hipStream_t stream)
{
  const void* tem   = d_in[0];
  const void* tmask = d_in[1];
  const void* ctx   = d_in[2];
  const void* cmask = d_in[3];
  const void* cls   = d_in[4];
  const int*  flag  = (const int*)d_in[5];
  const void* qe    = d_in[6];
  const void* ls    = d_in[7];
  const void* w1    = d_in[8];
  const void* b1    = d_in[9];
  const void* w2    = d_in[10];
  const void* b2    = d_in[11];

  int*   flags = (int*)d_ws;
  float* p     = (float*)d_ws + 16;
  float* sim   = p;  p += (size_t)NB*NL;
  float* tgts  = p;  p += (size_t)NB*NL;
  float* diss  = p;  p += (size_t)NB*NL;
  float* bgds  = p;  p += (size_t)NB*NL;
  float* src0f = p;  p += (size_t)384*ND;
  u16*   src0b = (u16*)p; p += (size_t)384*ND/2;
  u16*   hbf   = (u16*)p; p += (size_t)384*NH/2;
  float* fc2p  = p;  p += (size_t)4*384*ND;
  u16*   w1t   = (u16*)p; p += (size_t)ND*NH/2;
  u16*   w2t   = (u16*)p; p += (size_t)ND*NH/2;

  hipLaunchKernelGGL(k_presim, dim3(256 + 1152), dim3(256), 0, stream,
                     tem, tmask, ctx, cls, ls, w1, w2, w1t, w2t, sim, flags);
  hipLaunchKernelGGL(k_scores, dim3(NB), dim3(512), 0, stream, flags, sim, tmask, cmask, tgts, diss, bgds);
  hipLaunchKernelGGL(k_tok,    dim3(NB, 3), dim3(256), 0, stream,
                     flags, tem, ctx, cls, qe, tgts, diss, bgds, src0f, src0b);
  hipLaunchKernelGGL(k_fc1,    dim3(NH/64, 384/64), dim3(256), 0, stream, flags, src0b, w1t, b1, hbf);
  hipLaunchKernelGGL(k_fc2,    dim3(ND/64, 384/64, 4), dim3(256), 0, stream, flags, hbf, w2t, fc2p);
  hipLaunchKernelGGL(k_fin,    dim3(384*ND/1024), dim3(256), 0, stream,
                     flags, fc2p, b2, src0f, cls, qe, flag, d_out);
}

// Round 9
// 102.490 us; speedup vs baseline: 1.1294x; 1.0159x over previous
//
#include <hip/hip_runtime.h>
#include <hip/hip_bf16.h>
#include <math.h>

typedef unsigned short u16;
typedef unsigned int   u32;
typedef unsigned char  u8;

#define NB  128
#define NLT 64
#define NLC 400
#define NL  464
#define ND  768
#define NH  3072
#define NEGF (-1e20f)

typedef __attribute__((ext_vector_type(8))) short bf16x8;
typedef __attribute__((ext_vector_type(4))) float f32x4;

__device__ __forceinline__ float b2f(u16 u){ return __uint_as_float(((u32)u)<<16); }
__device__ __forceinline__ u16 f2b(float f){
  u32 x = __float_as_uint(f);
  x += 0x7fffu + ((x>>16)&1u);
  return (u16)(x>>16);
}
template<bool BF> __device__ __forceinline__ float ldf(const void* p, size_t i){
  if constexpr (BF) return b2f(((const u16*)p)[i]);
  else              return ((const float*)p)[i];
}

// ---------------------------------------------------------------- inline ABI detect
__device__ __forceinline__ void detect_inline(const void* tem, const void* tmask,
                                              int* sh2, int& bf, int& m8){
  int tid = threadIdx.x;
  if (tid < 64){
    const u16* p = (const u16*)tem;
    float acc = 0.f;
    for (int i = tid; i < 512; i += 64){
      float v = fabsf(b2f(p[i]));
      acc += fminf(v, 1e10f);               // NaN -> 1e10, inf clamped
    }
    for (int o = 32; o; o >>= 1) acc += __shfl_down(acc, o);
    const u8* mb = (const u8*)tmask;
    int nz = 0;
    for (int i = tid; i < 400; i += 64) if ((i & 3) != 0 && mb[i] != 0) nz = 1;
    unsigned long long anym = __ballot(nz);
    if (tid == 0){ sh2[0] = (acc < 1e4f) ? 1 : 0; sh2[1] = anym ? 1 : 0; }
  }
  __syncthreads();
  bf = sh2[0]; m8 = sh2[1];
}

// ---------------------------------------------------------------- sim: wave per row, contiguous loads
// Lane owns elems {seg*256 + lane*4 : seg=0..2}: every load instr is 64x16B (f32)
// or 64x8B (bf16) CONTIGUOUS. cls fragment in registers, reused per row.
// 2 rows/iter so the 4 shfl-reduce chains interleave.
template<bool BF>
__device__ void sim_body(const void* tem, const void* ctx, const void* cls,
                         const void* lsp, float* sim, int b, int h,
                         float* clsf, float* l4)
{
  int tid = threadIdx.x;
  for (int i = tid; i < ND; i += 256) clsf[i] = ldf<BF>(cls, (size_t)b*ND + i);
  __syncthreads();
  float ss = 0.f;
  for (int i = tid; i < ND; i += 256) ss += clsf[i]*clsf[i];
  #pragma unroll
  for (int o = 32; o; o >>= 1) ss += __shfl_xor(ss, o);
  if ((tid & 63) == 0) l4[tid >> 6] = ss;
  __syncthreads();
  float cn = fmaxf(sqrtf(l4[0]+l4[1]+l4[2]+l4[3]), 1e-12f);
  float escale = expf(ldf<BF>(lsp, 0));

  int lane = tid & 63, w = tid >> 6;
  float4 cv0 = ((const float4*)clsf)[lane];
  float4 cv1 = ((const float4*)clsf)[64 + lane];
  float4 cv2 = ((const float4*)clsf)[128 + lane];
  int base = h*232;

  auto dotrow = [&](int l, float& dd, float& rr){
    float4 v0, v1, v2;
    if constexpr (BF){
      const u16* row = (l < NLT) ? ((const u16*)tem + ((size_t)b*NLT + l)*ND)
                                 : ((const u16*)ctx + ((size_t)b*NLC + (l-NLT))*ND);
      ushort4 u0 = ((const ushort4*)row)[lane];
      ushort4 u1 = ((const ushort4*)row)[64 + lane];
      ushort4 u2 = ((const ushort4*)row)[128 + lane];
      v0 = make_float4(b2f(u0.x), b2f(u0.y), b2f(u0.z), b2f(u0.w));
      v1 = make_float4(b2f(u1.x), b2f(u1.y), b2f(u1.z), b2f(u1.w));
      v2 = make_float4(b2f(u2.x), b2f(u2.y), b2f(u2.z), b2f(u2.w));
    } else {
      const float* row = (l < NLT) ? ((const float*)tem + ((size_t)b*NLT + l)*ND)
                                   : ((const float*)ctx + ((size_t)b*NLC + (l-NLT))*ND);
      v0 = ((const float4*)row)[lane];
      v1 = ((const float4*)row)[64 + lane];
      v2 = ((const float4*)row)[128 + lane];
    }
    float d = v0.x*cv0.x, r = v0.x*v0.x;
    d = fmaf(v0.y, cv0.y, d); r = fmaf(v0.y, v0.y, r);
    d = fmaf(v0.z, cv0.z, d); r = fmaf(v0.z, v0.z, r);
    d = fmaf(v0.w, cv0.w, d); r = fmaf(v0.w, v0.w, r);
    d = fmaf(v1.x, cv1.x, d); r = fmaf(v1.x, v1.x, r);
    d = fmaf(v1.y, cv1.y, d); r = fmaf(v1.y, v1.y, r);
    d = fmaf(v1.z, cv1.z, d); r = fmaf(v1.z, v1.z, r);
    d = fmaf(v1.w, cv1.w, d); r = fmaf(v1.w, v1.w, r);
    d = fmaf(v2.x, cv2.x, d); r = fmaf(v2.x, v2.x, r);
    d = fmaf(v2.y, cv2.y, d); r = fmaf(v2.y, v2.y, r);
    d = fmaf(v2.z, cv2.z, d); r = fmaf(v2.z, v2.z, r);
    d = fmaf(v2.w, cv2.w, d); r = fmaf(v2.w, v2.w, r);
    dd = d; rr = r;
  };

  for (int i = 0; i < 58; i += 2){
    int l0 = base + i*4 + w;
    int l1 = base + (i+1)*4 + w;
    float d0, r0, d1, r1;
    dotrow(l0, d0, r0);
    dotrow(l1, d1, r1);
    #pragma unroll
    for (int o = 32; o; o >>= 1){
      d0 += __shfl_xor(d0, o); r0 += __shfl_xor(r0, o);
      d1 += __shfl_xor(d1, o); r1 += __shfl_xor(r1, o);
    }
    if (lane == 0){
      sim[(size_t)b*NL + l0] = d0/(cn*fmaxf(sqrtf(r0),1e-12f))*escale;
      sim[(size_t)b*NL + l1] = d1/(cn*fmaxf(sqrtf(r1),1e-12f))*escale;
    }
  }
}

// ---------------------------------------------------------------- fused sim + weight transpose
// grid 1408 flat: [0,256) sim (b = bid>>1, h = bid&1); [256,1408) transpose tiles.
__global__ __launch_bounds__(256) void k_presim(const void* tem, const void* tmask,
    const void* ctx, const void* cls, const void* lsp,
    const void* w1, const void* w2, u16* __restrict__ w1t, u16* __restrict__ w2t,
    float* sim, int* flags)
{
  __shared__ int sh2[2];
  __shared__ u16 tile[64][66];
  __shared__ float clsf[ND];
  __shared__ float l4[4];
  int bf, m8;
  detect_inline(tem, tmask, sh2, bf, m8);
  int bid = blockIdx.x;
  if (bid == 0 && threadIdx.x == 0){ flags[0] = bf; flags[1] = m8; }

  if (bid < 256){
    int b = bid >> 1, h = bid & 1;
    if (bf) sim_body<true >(tem, ctx, cls, lsp, sim, b, h, clsf, l4);
    else    sim_body<false>(tem, ctx, cls, lsp, sim, b, h, clsf, l4);
  } else {
    int t = bid - 256;
    int which = (t >= 576) ? 1 : 0;
    if (which) t -= 576;
    const void* W = which ? w2 : w1;
    u16* Wt = which ? w2t : w1t;
    int K = which ? NH : ND;     // source rows
    int N = which ? ND : NH;     // source cols
    int nt = N >> 6;
    int tk = t / nt, tn = t - tk*nt;
    int k0 = tk*64, n0 = tn*64;
    int r = threadIdx.x >> 6, c = threadIdx.x & 63;
    #pragma unroll
    for (int i = 0; i < 16; i++){
      int row = i*4 + r;
      size_t idx = (size_t)(k0 + row)*N + n0 + c;   // coalesced
      tile[row][c] = bf ? ((const u16*)W)[idx] : f2b(((const float*)W)[idx]);
    }
    __syncthreads();
    #pragma unroll
    for (int i = 0; i < 16; i++){
      int nrow = i*4 + r;
      Wt[(size_t)(n0 + nrow)*K + k0 + c] = tile[c][nrow];  // coalesced
    }
  }
}

// ---------------------------------------------------------------- fast 512-thread reductions
__device__ __forceinline__ float bsum512(float v, float* l8, int tid){
  #pragma unroll
  for (int o = 32; o; o >>= 1) v += __shfl_xor(v, o);
  __syncthreads();
  if ((tid & 63) == 0) l8[tid >> 6] = v;
  __syncthreads();
  float s = l8[0];
  #pragma unroll
  for (int i = 1; i < 8; i++) s += l8[i];
  return s;
}
__device__ __forceinline__ float bmax512(float v, float* l8, int tid){
  #pragma unroll
  for (int o = 32; o; o >>= 1) v = fmaxf(v, __shfl_xor(v, o));
  __syncthreads();
  if ((tid & 63) == 0) l8[tid >> 6] = v;
  __syncthreads();
  float s = l8[0];
  #pragma unroll
  for (int i = 1; i < 8; i++) s = fmaxf(s, l8[i]);
  return s;
}
__device__ __forceinline__ float bmin512(float v, float* l8, int tid){
  #pragma unroll
  for (int o = 32; o; o >>= 1) v = fminf(v, __shfl_xor(v, o));
  __syncthreads();
  if ((tid & 63) == 0) l8[tid >> 6] = v;
  __syncthreads();
  float s = l8[0];
  #pragma unroll
  for (int i = 1; i < 8; i++) s = fminf(s, l8[i]);
  return s;
}

// ---------------------------------------------------------------- scores
template<bool M8>
__device__ void scores_body(const float* sim, const void* tmask, const void* cmask,
                            float* tgts, float* diss, float* bgds,
                            float* srt, float* wsum, float* l8)
{
  int b = blockIdx.x, tid = threadIdx.x;
  int lane = tid & 63, wid = tid >> 6;
  bool valid = tid < NL;
  float sv = valid ? sim[(size_t)b*NL + tid] : 0.f;
  bool mk = false;
  if (valid){
    if constexpr (M8)
      mk = (tid < NLT) ? (((const u8*)tmask)[b*NLT + tid] != 0)
                       : (((const u8*)cmask)[b*NLC + tid - NLT] != 0);
    else
      mk = (tid < NLT) ? (((const int*)tmask)[b*NLT + tid] != 0)
                       : (((const int*)cmask)[b*NLC + tid - NLT] != 0);
  }
  float lt = (valid && mk) ? sv : NEGF;
  float m1 = bmax512(lt, l8, tid);
  float e1 = valid ? expf(lt - m1) : 0.f;
  float s1 = bsum512(e1, l8, tid);
  if (valid) tgts[(size_t)b*NL + tid] = e1/s1;

  float bl = (valid && !mk) ? sv : NEGF;
  float m2 = bmax512(bl, l8, tid);
  float e2 = valid ? expf(bl - m2) : 0.f;
  float s2 = bsum512(e2, l8, tid);
  float bg0 = e2/s2;

  // bitonic sort ascending; pads carry +inf
  float v = valid ? bg0 : INFINITY;
  for (int k = 2; k <= 512; k <<= 1){
    for (int j = k >> 1; j >= 64; j >>= 1){
      __syncthreads();
      srt[tid] = v;
      __syncthreads();
      float p = srt[tid ^ j];
      bool up = ((tid & k) == 0), lower = ((tid & j) == 0);
      v = (up == lower) ? fminf(v, p) : fmaxf(v, p);
    }
    int j0 = (k >> 1) < 32 ? (k >> 1) : 32;
    for (int j = j0; j >= 1; j >>= 1){
      float p = __shfl_xor(v, j);
      bool up = ((tid & k) == 0), lower = ((tid & j) == 0);
      v = (up == lower) ? fminf(v, p) : fmaxf(v, p);
    }
  }
  // inclusive scan
  float c = v;
  #pragma unroll
  for (int o = 1; o < 64; o <<= 1){
    float t = __shfl_up(c, o);
    if (lane >= o) c += t;
  }
  __syncthreads();
  if (lane == 63) wsum[wid] = c;
  __syncthreads();
  float off = 0.f;
  for (int i = 0; i < wid; i++) off += wsum[i];
  c += off;
  float cand = (c < 0.25f) ? 1.0f : v;
  float thr = bmin512(cand, l8, tid);

  bool dm = valid && (bg0 >= thr);
  float dl = dm ? bl : NEGF;
  float l2 = dm ? NEGF : bl;
  float m3 = bmax512(dl, l8, tid);
  float e3 = valid ? expf(dl - m3) : 0.f;
  float s3 = bsum512(e3, l8, tid);
  if (valid) diss[(size_t)b*NL + tid] = e3/s3;
  float m4 = bmax512(l2, l8, tid);
  float e4 = valid ? expf(l2 - m4) : 0.f;
  float s4 = bsum512(e4, l8, tid);
  if (valid) bgds[(size_t)b*NL + tid] = e4/s4;
}
__global__ __launch_bounds__(512) void k_scores(const int* flags, const float* sim,
    const void* tmask, const void* cmask, float* tgts, float* diss, float* bgds){
  __shared__ float srt[512];
  __shared__ float wsum[8];
  __shared__ float l8[8];
  if (flags[1]) scores_body<true >(sim, tmask, cmask, tgts, diss, bgds, srt, wsum, l8);
  else          scores_body<false>(sim, tmask, cmask, tgts, diss, bgds, srt, wsum, l8);
}

// ---------------------------------------------------------------- tokens + src0 (fused)
template<bool BF>
__device__ void tok_body(const void* tem, const void* ctx, const void* cls, const void* qe,
                         const float* __restrict__ tgts, const float* __restrict__ diss,
                         const float* __restrict__ bgds,
                         float* __restrict__ src0f, u16* __restrict__ src0b,
                         float (*ws)[NL], float (*red)[3][264])
{
  int b = blockIdx.x, dc = blockIdx.y, tid = threadIdx.x;
  int g = tid >> 5, l32 = tid & 31;
  int c0 = dc*256 + l32*8;
  for (int i = tid; i < NL; i += 256){
    ws[0][i] = tgts[(size_t)b*NL + i];
    ws[1][i] = diss[(size_t)b*NL + i];
    ws[2][i] = bgds[(size_t)b*NL + i];
  }
  __syncthreads();
  float acc[3][8];
  #pragma unroll
  for (int j = 0; j < 3; j++)
    #pragma unroll
    for (int q = 0; q < 8; q++) acc[j][q] = 0.f;

  for (int it = 0; it < 58; it++){
    int l = it*8 + g;
    float f[8];
    if constexpr (BF){
      const u16* row = (l < NLT) ? ((const u16*)tem + ((size_t)b*NLT + l)*ND)
                                 : ((const u16*)ctx + ((size_t)b*NLC + (l-NLT))*ND);
      uint4 v = *(const uint4*)(row + c0);
      f[0]=b2f((u16)(v.x&0xffff)); f[1]=b2f((u16)(v.x>>16));
      f[2]=b2f((u16)(v.y&0xffff)); f[3]=b2f((u16)(v.y>>16));
      f[4]=b2f((u16)(v.z&0xffff)); f[5]=b2f((u16)(v.z>>16));
      f[6]=b2f((u16)(v.w&0xffff)); f[7]=b2f((u16)(v.w>>16));
    } else {
      const float* row = (l < NLT) ? ((const float*)tem + ((size_t)b*NLT + l)*ND)
                                   : ((const float*)ctx + ((size_t)b*NLC + (l-NLT))*ND);
      float4 v0 = *(const float4*)(row + c0);
      float4 v1 = *(const float4*)(row + c0 + 4);
      f[0]=v0.x; f[1]=v0.y; f[2]=v0.z; f[3]=v0.w;
      f[4]=v1.x; f[5]=v1.y; f[6]=v1.z; f[7]=v1.w;
    }
    float w0 = ws[0][l], w1 = ws[1][l], w2 = ws[2][l];
    #pragma unroll
    for (int q = 0; q < 8; q++){
      acc[0][q] = fmaf(w0, f[q], acc[0][q]);
      acc[1][q] = fmaf(w1, f[q], acc[1][q]);
      acc[2][q] = fmaf(w2, f[q], acc[2][q]);
    }
  }
  #pragma unroll
  for (int j = 0; j < 3; j++)
    #pragma unroll
    for (int q = 0; q < 8; q++) red[g][j][l32*8 + q] = acc[j][q];
  __syncthreads();
  int col = dc*256 + tid;
  #pragma unroll
  for (int j = 0; j < 3; j++){
    float s = 0.f;
    #pragma unroll
    for (int g2 = 0; g2 < 8; g2++) s += red[g2][j][tid];
    s += ldf<BF>(qe, (size_t)j*ND + col);
    if (j == 0) s += ldf<BF>(cls, (size_t)b*ND + col);
    size_t oi = ((size_t)b*3 + j)*ND + col;
    src0f[oi] = s;
    src0b[oi] = f2b(s);
  }
}
__global__ __launch_bounds__(256) void k_tok(const int* flags, const void* tem,
    const void* ctx, const void* cls, const void* qe,
    const float* tgts, const float* diss, const float* bgds,
    float* src0f, u16* src0b){
  __shared__ float ws[3][NL];
  __shared__ float red[8][3][264];
  if (flags[0]) tok_body<true >(tem, ctx, cls, qe, tgts, diss, bgds, src0f, src0b, ws, red);
  else          tok_body<false>(tem, ctx, cls, qe, tgts, diss, bgds, src0f, src0b, ws, red);
}

// ---------------------------------------------------------------- MFMA GEMM core
// Both operands bf16 with [row][K] layout (B pre-transposed). 2-phase dbuf.
__device__ __forceinline__ void mfma_loop2(const u16* __restrict__ A, int lda,
                                           const u16* __restrict__ B, int ldb,
                                           int m0, int n0, int kb_, int ke_,
                                           u16* lds, f32x4 (&acc)[2][2])
{
  int tid = threadIdx.x, lane = tid & 63;
  int w = tid >> 6, wr = w >> 1, wc = w & 1;
  #pragma unroll
  for (int i = 0; i < 2; i++)
    #pragma unroll
    for (int j = 0; j < 2; j++) acc[i][j] = (f32x4){0.f,0.f,0.f,0.f};

  int rS = tid >> 2, kcS = (tid & 3) * 16;
  uint4 a0, a1, b0, b1;
  auto LOAD = [&](int k0){
    const uint4* pa = (const uint4*)(A + (size_t)(m0 + rS)*lda + k0 + kcS);
    a0 = pa[0]; a1 = pa[1];
    const uint4* pb = (const uint4*)(B + (size_t)(n0 + rS)*ldb + k0 + kcS);
    b0 = pb[0]; b1 = pb[1];
  };
  auto WRITE = [&](u16* L){
    u32 sw = (u32)((rS & 7) << 4);
    u32 ba = (u32)(rS*128 + kcS*2);
    *(uint4*)((char*)L + (ba ^ sw)) = a0;
    *(uint4*)((char*)L + ((ba + 16) ^ sw)) = a1;
    *(uint4*)((char*)L + 8192 + (ba ^ sw)) = b0;
    *(uint4*)((char*)L + 8192 + ((ba + 16) ^ sw)) = b1;
  };

  int nt = (ke_ - kb_) >> 6;
  LOAD(kb_);
  WRITE(lds);
  __syncthreads();
  int cur = 0;
  for (int t = 0; t < nt; t++){
    if (t + 1 < nt) LOAD(kb_ + (t+1)*64);
    u16* L = lds + (size_t)cur*8192;
    #pragma unroll
    for (int kb = 0; kb < 2; kb++){
      bf16x8 af[2], bfr[2];
      #pragma unroll
      for (int i = 0; i < 2; i++){
        int ml = wr*32 + i*16 + (lane & 15);
        u32 ab = (u32)(ml*128 + kb*64 + (lane >> 4)*16) ^ (u32)((ml & 7) << 4);
        af[i] = *(const bf16x8*)((char*)L + ab);
        int cl = wc*32 + i*16 + (lane & 15);
        u32 bb = (u32)(cl*128 + kb*64 + (lane >> 4)*16) ^ (u32)((cl & 7) << 4);
        bfr[i] = *(const bf16x8*)((char*)L + 8192 + bb);
      }
      #pragma unroll
      for (int i = 0; i < 2; i++)
        #pragma unroll
        for (int j = 0; j < 2; j++)
          acc[i][j] = __builtin_amdgcn_mfma_f32_16x16x32_bf16(af[i], bfr[j], acc[i][j], 0, 0, 0);
    }
    if (t + 1 < nt) WRITE(lds + (size_t)(cur^1)*8192);
    __syncthreads();
    cur ^= 1;
  }
}

// fc1: h = gelu(src0b @ w1 + b1), bf16 out. grid (NH/64, 384/64)
template<bool BF>
__device__ void fc1_body(const u16* src0b, const u16* w1t, const void* b1, u16* hbf, u16* lds){
  int n0 = blockIdx.x*64, m0 = blockIdx.y*64;
  f32x4 acc[2][2];
  mfma_loop2(src0b, ND, w1t, ND, m0, n0, 0, ND, lds, acc);
  int lane = threadIdx.x & 63, w = threadIdx.x >> 6, wr = w >> 1, wc = w & 1;
  #pragma unroll
  for (int j = 0; j < 2; j++){
    int n = n0 + wc*32 + j*16 + (lane & 15);
    float bb = ldf<BF>(b1, n);
    #pragma unroll
    for (int i = 0; i < 2; i++){
      int mb = m0 + wr*32 + i*16 + (lane >> 4)*4;
      #pragma unroll
      for (int r = 0; r < 4; r++){
        float x = acc[i][j][r] + bb;
        float g = 0.5f*x*(1.0f + erff(x*0.70710678118654752f));
        hbf[(size_t)(mb + r)*NH + n] = f2b(g);
      }
    }
  }
}
__global__ __launch_bounds__(256) void k_fc1(const int* flags, const u16* src0b,
    const u16* w1t, const void* b1, u16* hbf){
  __shared__ u16 lds[16384];
  if (flags[0]) fc1_body<true >(src0b, w1t, b1, hbf, lds);
  else          fc1_body<false>(src0b, w1t, b1, hbf, lds);
}

// fc2 partials: grid (ND/64, 384/64, 4)
__global__ __launch_bounds__(256) void k_fc2(const int* flags, const u16* hbf,
    const u16* w2t, float* fc2p){
  __shared__ u16 lds[16384];
  int n0 = blockIdx.x*64, m0 = blockIdx.y*64, z = blockIdx.z;
  f32x4 acc[2][2];
  mfma_loop2(hbf, NH, w2t, NH, m0, n0, z*768, (z+1)*768, lds, acc);
  int lane = threadIdx.x & 63, w = threadIdx.x >> 6, wr = w >> 1, wc = w & 1;
  float* po = fc2p + (size_t)z*(384*ND);
  #pragma unroll
  for (int j = 0; j < 2; j++){
    int n = n0 + wc*32 + j*16 + (lane & 15);
    #pragma unroll
    for (int i = 0; i < 2; i++){
      int mb = m0 + wr*32 + i*16 + (lane >> 4)*4;
      #pragma unroll
      for (int r = 0; r < 4; r++)
        po[(size_t)(mb + r)*ND + n] = acc[i][j][r];
    }
  }
}

// ---------------------------------------------------------------- fc2 epilogue
template<bool BF>
__device__ void fin_body(const float* __restrict__ p, const void* b2,
                         const float* __restrict__ src0f, const void* cls,
                         const void* qe, const int* flag, void* out){
  int idx = (blockIdx.x*256 + threadIdx.x)*4;
  int r = idx / ND;
  int n = idx % ND;
  float s[4] = {0,0,0,0};
  #pragma unroll
  for (int ksp = 0; ksp < 4; ksp++){
    float4 v = *(const float4*)(p + (size_t)ksp*(384*ND) + idx);
    s[0]+=v.x; s[1]+=v.y; s[2]+=v.z; s[3]+=v.w;
  }
  float4 res = *(const float4*)(src0f + idx);
  const float* rp = &res.x;
  int bi = r/3, j = r - bi*3;
  bool take_src_ = (flag[bi] == 1);
  #pragma unroll
  for (int jj = 0; jj < 4; jj++){
    float val = s[jj] + ldf<BF>(b2, n + jj) + rp[jj];
    if (take_src_){
      val = ldf<BF>(qe, (size_t)j*ND + n + jj)
          + ((j == 0) ? ldf<BF>(cls, (size_t)bi*ND + n + jj) : 0.f);
    }
    s[jj] = val;
  }
  if constexpr (BF){
    ushort4 o = { f2b(s[0]), f2b(s[1]), f2b(s[2]), f2b(s[3]) };
    *(ushort4*)((u16*)out + idx) = o;
  } else {
    float4 o = {s[0], s[1], s[2], s[3]};
    *(float4*)((float*)out + idx) = o;
  }
}
__global__ __launch_bounds__(256) void k_fin(const int* flags, const float* p,
    const void* b2, const float* src0f, const void* cls, const void* qe,
    const int* flag, void* out){
  if (flags[0]) fin_body<true >(p, b2, src0f, cls, qe, flag, out);
  else          fin_body<false>(p, b2, src0f, cls, qe, flag, out);
}

// ---------------------------------------------------------------- launch
extern "C" void kernel_launch(void* const* d_in, const int* in_sizes, int n_in,
                              void* d_out, int out_size, void* d_ws, size_t ws_size,
                              hipStream_t stream)
{
  const void* tem   = d_in[0];
  const void* tmask = d_in[1];
  const void* ctx   = d_in[2];
  const void* cmask = d_in[3];
  const void* cls   = d_in[4];
  const int*  flag  = (const int*)d_in[5];
  const void* qe    = d_in[6];
  const void* ls    = d_in[7];
  const void* w1    = d_in[8];
  const void* b1    = d_in[9];
  const void* w2    = d_in[10];
  const void* b2    = d_in[11];

  int*   flags = (int*)d_ws;
  float* p     = (float*)d_ws + 16;
  float* sim   = p;  p += (size_t)NB*NL;
  float* tgts  = p;  p += (size_t)NB*NL;
  float* diss  = p;  p += (size_t)NB*NL;
  float* bgds  = p;  p += (size_t)NB*NL;
  float* src0f = p;  p += (size_t)384*ND;
  u16*   src0b = (u16*)p; p += (size_t)384*ND/2;
  u16*   hbf   = (u16*)p; p += (size_t)384*NH/2;
  float* fc2p  = p;  p += (size_t)4*384*ND;
  u16*   w1t   = (u16*)p; p += (size_t)ND*NH/2;
  u16*   w2t   = (u16*)p; p += (size_t)ND*NH/2;

  hipLaunchKernelGGL(k_presim, dim3(256 + 1152), dim3(256), 0, stream,
                     tem, tmask, ctx, cls, ls, w1, w2, w1t, w2t, sim, flags);
  hipLaunchKernelGGL(k_scores, dim3(NB), dim3(512), 0, stream, flags, sim, tmask, cmask, tgts, diss, bgds);
  hipLaunchKernelGGL(k_tok,    dim3(NB, 3), dim3(256), 0, stream,
                     flags, tem, ctx, cls, qe, tgts, diss, bgds, src0f, src0b);
  hipLaunchKernelGGL(k_fc1,    dim3(NH/64, 384/64), dim3(256), 0, stream, flags, src0b, w1t, b1, hbf);
  hipLaunchKernelGGL(k_fc2,    dim3(ND/64, 384/64, 4), dim3(256), 0, stream, flags, hbf, w2t, fc2p);
  hipLaunchKernelGGL(k_fin,    dim3(384*ND/1024), dim3(256), 0, stream,
                     flags, fc2p, b2, src0f, cls, qe, flag, d_out);
}